// Round 2
// baseline (443.610 us; speedup 1.0000x reference)
//
#include <hip/hip_runtime.h>

// VectorQuantizer: N=65536 rows (64*1024), D=128, K=1024 codewords, all f32.
// d_out (ALL read back as float32): quantized (8388608) | indices-as-float (65536) | loss (1)

constexpr int N_ROWS = 65536;
constexpr int K_CODES = 1024;
constexpr int D = 128;
constexpr int BM = 64;               // rows per block
constexpr int BK = 64;               // codeword chunk
constexpr int LDS_STRIDE = D + 4;    // 132 floats: keeps float4 alignment, 2-way conflicts max

// ---------------------------------------------------------------------------
// Kernel 1: codeword squared norms; thread (0,0) also zeroes the loss accum.
__global__ __launch_bounds__(64) void vq_cnorm(const float* __restrict__ cw,
                                               float* __restrict__ cnorm,
                                               double* __restrict__ loss_acc) {
    const int k = blockIdx.x;
    const int lane = threadIdx.x;
    float2 v = reinterpret_cast<const float2*>(cw + (size_t)k * D)[lane];
    float s = v.x * v.x + v.y * v.y;
#pragma unroll
    for (int off = 32; off; off >>= 1) s += __shfl_down(s, off, 64);
    if (lane == 0) cnorm[k] = s;
    if (lane == 0 && k == 0) *loss_acc = 0.0;
}

// ---------------------------------------------------------------------------
// Kernel 2: argmin over codewords. score = ||c||^2 - 2 x.c  (row term dropped).
// Indices are written as FLOAT values (harness reads whole d_out as f32).
__global__ __launch_bounds__(256) void vq_argmin(const float* __restrict__ x,
                                                 const float* __restrict__ cw,
                                                 const float* __restrict__ cnorm,
                                                 float* __restrict__ out_idx_f) {
    __shared__ float Xs[BM][LDS_STRIDE];
    __shared__ float Cs[BK][LDS_STRIDE];

    const int tid = threadIdx.x;
    const int tx = tid & 15;          // codeword-group lane (16)
    const int ty = tid >> 4;          // row group (16)
    const int row_base = blockIdx.x * BM;

    // Stage X tile (64 rows x 128 f32) — 2048 float4s, coalesced.
    const float4* gx = reinterpret_cast<const float4*>(x + (size_t)row_base * D);
#pragma unroll
    for (int i = 0; i < 8; ++i) {
        int l = tid + i * 256;
        int r = l >> 5, d4 = l & 31;
        *reinterpret_cast<float4*>(&Xs[r][d4 * 4]) = gx[l];
    }

    float bv[4];
    int bi[4];
#pragma unroll
    for (int r = 0; r < 4; ++r) { bv[r] = 3.4e38f; bi[r] = 0; }

    for (int chunk = 0; chunk < K_CODES / BK; ++chunk) {
        __syncthreads();
        const float4* gc = reinterpret_cast<const float4*>(cw + (size_t)chunk * BK * D);
#pragma unroll
        for (int i = 0; i < 8; ++i) {
            int l = tid + i * 256;
            int r = l >> 5, d4 = l & 31;
            *reinterpret_cast<float4*>(&Cs[r][d4 * 4]) = gc[l];
        }
        __syncthreads();

        float acc[4][4];
#pragma unroll
        for (int r = 0; r < 4; ++r)
#pragma unroll
            for (int j = 0; j < 4; ++j) acc[r][j] = 0.f;

#pragma unroll 4
        for (int d4 = 0; d4 < 32; ++d4) {
            float4 a[4], c[4];
#pragma unroll
            for (int r = 0; r < 4; ++r)
                a[r] = *reinterpret_cast<const float4*>(&Xs[ty * 4 + r][d4 * 4]);
#pragma unroll
            for (int j = 0; j < 4; ++j)
                c[j] = *reinterpret_cast<const float4*>(&Cs[j * 16 + tx][d4 * 4]);
#pragma unroll
            for (int r = 0; r < 4; ++r)
#pragma unroll
                for (int j = 0; j < 4; ++j) {
                    acc[r][j] += a[r].x * c[j].x;
                    acc[r][j] += a[r].y * c[j].y;
                    acc[r][j] += a[r].z * c[j].z;
                    acc[r][j] += a[r].w * c[j].w;
                }
        }

        // score + running argmin (cols strictly increasing per thread -> first-min kept)
#pragma unroll
        for (int j = 0; j < 4; ++j) {
            int col = chunk * BK + j * 16 + tx;
            float cn = cnorm[col];
#pragma unroll
            for (int r = 0; r < 4; ++r) {
                float sc = cn - 2.f * acc[r][j];
                if (sc < bv[r]) { bv[r] = sc; bi[r] = col; }
            }
        }
    }

    // Reduce (val,idx) lexicographic min across the 16 tx lanes sharing each row.
#pragma unroll
    for (int r = 0; r < 4; ++r) {
#pragma unroll
        for (int off = 1; off < 16; off <<= 1) {
            float ov = __shfl_xor(bv[r], off, 64);
            int oi = __shfl_xor(bi[r], off, 64);
            if (ov < bv[r] || (ov == bv[r] && oi < bi[r])) { bv[r] = ov; bi[r] = oi; }
        }
        if (tx == 0) out_idx_f[row_base + ty * 4 + r] = (float)bi[r];
    }
}

// ---------------------------------------------------------------------------
// Kernel 3: gather codewords, write straight-through output, reduce sq error.
// Reads indices back from their float encoding (exact for 0..1023).
__global__ __launch_bounds__(256) void vq_gather_loss(const float* __restrict__ x,
                                                      const float* __restrict__ cw,
                                                      const float* __restrict__ idx_f,
                                                      float* __restrict__ qout,
                                                      double* __restrict__ loss_acc) {
    const int total4 = N_ROWS * D / 4;  // 2,097,152 float4
    double lsum = 0.0;
    for (int i = blockIdx.x * blockDim.x + threadIdx.x; i < total4;
         i += gridDim.x * blockDim.x) {
        int n = i >> 5;      // row
        int d4 = i & 31;     // float4 within row
        int k = (int)idx_f[n];
        float4 q = reinterpret_cast<const float4*>(cw + (size_t)k * D)[d4];
        float4 xv = reinterpret_cast<const float4*>(x)[i];
        // straight-through value: x + (q - x), matching reference arithmetic
        float dxx = q.x - xv.x, dxy = q.y - xv.y, dxz = q.z - xv.z, dxw = q.w - xv.w;
        float4 o;
        o.x = xv.x + dxx; o.y = xv.y + dxy; o.z = xv.z + dxz; o.w = xv.w + dxw;
        reinterpret_cast<float4*>(qout)[i] = o;
        float sq = dxx * dxx + dxy * dxy + dxz * dxz + dxw * dxw;
        lsum += (double)sq;
    }
#pragma unroll
    for (int off = 32; off; off >>= 1) lsum += __shfl_down(lsum, off, 64);
    if ((threadIdx.x & 63) == 0) atomicAdd(loss_acc, lsum);
}

// ---------------------------------------------------------------------------
// Kernel 4: finalize loss = 1.25 * mean(sq err)
__global__ void vq_finalize(const double* __restrict__ loss_acc,
                            float* __restrict__ out_loss) {
    *out_loss = (float)(*loss_acc * (1.25 / (double)((size_t)N_ROWS * D)));
}

// ---------------------------------------------------------------------------
extern "C" void kernel_launch(void* const* d_in, const int* in_sizes, int n_in,
                              void* d_out, int out_size, void* d_ws, size_t ws_size,
                              hipStream_t stream) {
    const float* x = (const float*)d_in[0];       // (64,1024,128)
    const float* cw = (const float*)d_in[1];      // (1024,128)

    float* qout = (float*)d_out;                                    // 8388608 f32
    float* out_idx_f = (float*)d_out + (size_t)N_ROWS * D;          // 65536 f32 (index values)
    float* out_loss = (float*)d_out + (size_t)N_ROWS * D + N_ROWS;  // 1 f32

    float* cnorm = (float*)d_ws;                              // 1024 f32
    double* loss_acc = (double*)((char*)d_ws + 8192);         // 1 f64, aligned

    vq_cnorm<<<K_CODES, 64, 0, stream>>>(cw, cnorm, loss_acc);
    vq_argmin<<<N_ROWS / BM, 256, 0, stream>>>(x, cw, cnorm, out_idx_f);
    vq_gather_loss<<<2048, 256, 0, stream>>>(x, cw, out_idx_f, qout, loss_acc);
    vq_finalize<<<1, 1, 0, stream>>>(loss_acc, out_loss);
}

// Round 3
// 335.668 us; speedup vs baseline: 1.3216x; 1.3216x over previous
//
#include <hip/hip_runtime.h>
#include <stdint.h>

// VectorQuantizer: N=65536 rows, D=128, K=1024 codewords, f32.
// d_out (all f32): quantized (8388608) | indices-as-float (65536) | loss (1)
//
// Strategy: score = ||c||^2 - 2 x.c via bf16-split MFMA (hi*hi + hi*lo + lo*hi),
// fused per-row top-2 argmin; rows with margin < MARGIN exactly re-ranked in f32.

typedef short     bf16x8 __attribute__((ext_vector_type(8)));
typedef float     f32x4  __attribute__((ext_vector_type(4)));
typedef unsigned short u16x8 __attribute__((ext_vector_type(8)));
typedef unsigned short u16x2 __attribute__((ext_vector_type(2)));

constexpr int N_ROWS = 65536;
constexpr int K_CODES = 1024;
constexpr int D = 128;
constexpr float MARGIN = 0.03f;   // >> 30x worst-case bf16-split score error (~1e-3)

__device__ __forceinline__ unsigned short f32_to_bf16_rn(float f) {
    unsigned u = __float_as_uint(f);
    unsigned r = (u + 0x7FFFu + ((u >> 16) & 1u)) >> 16;
    return (unsigned short)r;
}
__device__ __forceinline__ float bf16_to_f32(unsigned short h) {
    return __uint_as_float(((unsigned)h) << 16);
}

__device__ __forceinline__ void gload_lds16(const void* g, void* l) {
    __builtin_amdgcn_global_load_lds(
        (const __attribute__((address_space(1))) unsigned int*)g,
        (__attribute__((address_space(3))) unsigned int*)l, 16, 0, 0);
}

// ---------------------------------------------------------------------------
// Prep 1: codeword norms (f32, same math as verified R2) + bf16 hi/lo planes.
// Cp layout: [plane(2)][1024][128] bf16, plane stride 131072 elems.
__global__ __launch_bounds__(64) void vq_prep_cw(const float* __restrict__ cw,
                                                 unsigned short* __restrict__ Cp,
                                                 float* __restrict__ cnorm,
                                                 int* __restrict__ rcnt) {
    const int k = blockIdx.x;
    const int lane = threadIdx.x;
    float2 v = reinterpret_cast<const float2*>(cw + (size_t)k * D)[lane];
    float s = v.x * v.x + v.y * v.y;
#pragma unroll
    for (int off = 32; off; off >>= 1) s += __shfl_down(s, off, 64);
    if (lane == 0) cnorm[k] = s;
    if (lane == 0 && k == 0) *rcnt = 0;

    unsigned short hx = f32_to_bf16_rn(v.x), hy = f32_to_bf16_rn(v.y);
    unsigned short lx = f32_to_bf16_rn(v.x - bf16_to_f32(hx));
    unsigned short ly = f32_to_bf16_rn(v.y - bf16_to_f32(hy));
    size_t off0 = (size_t)k * D + lane * 2;
    u16x2 hv; hv[0] = hx; hv[1] = hy;
    u16x2 lv; lv[0] = lx; lv[1] = ly;
    *reinterpret_cast<u16x2*>(Cp + off0) = hv;
    *reinterpret_cast<u16x2*>(Cp + 131072 + off0) = lv;
}

// ---------------------------------------------------------------------------
// Prep 2: X bf16 hi/lo planes, k-major: Xp[plane][s(4)][row(65536)][32 elems]
// so a wave's A-fragment load (16 rows x 16B) is one dense 1 KiB burst.
__global__ __launch_bounds__(256) void vq_prep_x(const float* __restrict__ x,
                                                 unsigned short* __restrict__ Xp) {
    const size_t planeElems = (size_t)4 * 65536 * 32;  // 8388608
    int i = blockIdx.x * 256 + threadIdx.x;            // 0 .. 1048575
    int row = i >> 4;
    int g = i & 15;
    int s = g >> 2;
    int e0 = (g & 3) * 8;
    const float4* xf4 = reinterpret_cast<const float4*>(x);
    float4 f0 = xf4[i * 2];
    float4 f1 = xf4[i * 2 + 1];
    float in[8] = {f0.x, f0.y, f0.z, f0.w, f1.x, f1.y, f1.z, f1.w};
    u16x8 hv, lv;
#pragma unroll
    for (int e = 0; e < 8; ++e) {
        unsigned short h = f32_to_bf16_rn(in[e]);
        hv[e] = h;
        lv[e] = f32_to_bf16_rn(in[e] - bf16_to_f32(h));
    }
    size_t off = ((size_t)s * 65536 + row) * 32 + e0;
    *reinterpret_cast<u16x8*>(Xp + off) = hv;
    *reinterpret_cast<u16x8*>(Xp + planeElems + off) = lv;
}

// ---------------------------------------------------------------------------
// Main: fused MFMA score + per-row top-2 argmin.
// Block = 256 thr (4 waves), BM=128 rows (32/wave), chunks of 64 codewords.
// A (X) fragments live in registers; B (C) double-buffered in LDS, staged via
// global_load_lds with pre-swizzled source (read-side XOR (col&7)<<4 on kbyte).
__global__ __launch_bounds__(256, 2) void vq_argmin_mfma(
    const unsigned short* __restrict__ Xp,
    const unsigned short* __restrict__ Cp,
    const float* __restrict__ cnorm,
    float* __restrict__ out_idx_f,
    int* __restrict__ rcnt,
    int* __restrict__ repair_rows) {
    __shared__ unsigned char Bs[2][2][16384];  // [buf][plane][col*256 + swz kbyte]

    const int tid = threadIdx.x;
    const int wave = tid >> 6;
    const int lane = tid & 63;
    const int l15 = lane & 15;
    const int lg = lane >> 4;
    const int wrow = blockIdx.x * 128 + wave * 32;

    // ---- A fragments from global (dense k-major layout), kept in registers.
    const size_t planeElems = (size_t)4 * 65536 * 32;
    bf16x8 A[2][4][2];
#pragma unroll
    for (int r2 = 0; r2 < 2; ++r2) {
        int row = wrow + r2 * 16 + l15;
#pragma unroll
        for (int s = 0; s < 4; ++s) {
            size_t base = ((size_t)s * 65536 + row) * 32 + lg * 8;
            A[r2][s][0] = *reinterpret_cast<const bf16x8*>(Xp + base);
            A[r2][s][1] = *reinterpret_cast<const bf16x8*>(Xp + planeElems + base);
        }
    }

    float bv[2][4], bv2[2][4];
    int bi[2][4];
#pragma unroll
    for (int r2 = 0; r2 < 2; ++r2)
#pragma unroll
        for (int i = 0; i < 4; ++i) { bv[r2][i] = 3.4e38f; bv2[r2][i] = 3.4e38f; bi[r2][i] = 0; }

    // Staging: 32 gload_lds16 per block-chunk; wave w issues t = w*8+u.
    // LDS[pl][cwl][q] = C[pl][chunk*64+cwl][q ^ ((cwl&7)<<4)]  (q = byte 0..255)
    const char* Cpb = reinterpret_cast<const char*>(Cp);
    auto stageB = [&](int c, int b) {
#pragma unroll
        for (int u = 0; u < 8; ++u) {
            int t = wave * 8 + u;
            int pl = t >> 4;
            int cwl = (t & 15) * 4 + lg;
            int q = l15 * 16;
            const char* src = Cpb + pl * 262144 + ((size_t)(c * 64 + cwl)) * 256
                              + (q ^ ((cwl & 7) << 4));
            void* dst = (void*)&Bs[b][pl][(t & 15) * 1024];
            gload_lds16(src, dst);
        }
    };

    // Per-lane read addressing within a plane (swizzled):
    const int cbase = l15 * 256;
    const int swz = (l15 & 7) << 4;
    int kb[4];
#pragma unroll
    for (int s = 0; s < 4; ++s) kb[s] = (s * 64 + lg * 16) ^ swz;

    stageB(0, 0);
    asm volatile("s_waitcnt vmcnt(0)" ::: "memory");
    __syncthreads();

    for (int c = 0; c < 16; ++c) {
        const int buf = c & 1;
        if (c < 15) stageB(c + 1, buf ^ 1);

        f32x4 acc[2][4];
#pragma unroll
        for (int r2 = 0; r2 < 2; ++r2)
#pragma unroll
            for (int j = 0; j < 4; ++j) acc[r2][j] = (f32x4)(0.f);

#pragma unroll
        for (int s = 0; s < 4; ++s) {
            bf16x8 bh[4], bl[4];
#pragma unroll
            for (int j = 0; j < 4; ++j) {
                int ad = j * 4096 + cbase + kb[s];
                bh[j] = *reinterpret_cast<const bf16x8*>(&Bs[buf][0][ad]);
                bl[j] = *reinterpret_cast<const bf16x8*>(&Bs[buf][1][ad]);
            }
#pragma unroll
            for (int r2 = 0; r2 < 2; ++r2)
#pragma unroll
                for (int j = 0; j < 4; ++j) {
                    acc[r2][j] = __builtin_amdgcn_mfma_f32_16x16x32_bf16(
                        A[r2][s][0], bh[j], acc[r2][j], 0, 0, 0);
                    acc[r2][j] = __builtin_amdgcn_mfma_f32_16x16x32_bf16(
                        A[r2][s][0], bl[j], acc[r2][j], 0, 0, 0);
                    acc[r2][j] = __builtin_amdgcn_mfma_f32_16x16x32_bf16(
                        A[r2][s][1], bh[j], acc[r2][j], 0, 0, 0);
                }
        }

        // scores + running top-2 (cols ascend -> first-min kept per lane)
#pragma unroll
        for (int j = 0; j < 4; ++j) {
            int col = c * 64 + j * 16 + l15;
            float cn = cnorm[col];
#pragma unroll
            for (int r2 = 0; r2 < 2; ++r2)
#pragma unroll
                for (int i = 0; i < 4; ++i) {
                    float sc = cn - 2.f * acc[r2][j][i];
                    if (sc < bv[r2][i]) {
                        bv2[r2][i] = bv[r2][i];
                        bv[r2][i] = sc;
                        bi[r2][i] = col;
                    } else if (sc < bv2[r2][i]) {
                        bv2[r2][i] = sc;
                    }
                }
        }
        asm volatile("s_waitcnt vmcnt(0)" ::: "memory");
        __syncthreads();
    }

    // Cross-lane top-2 merge over the 16 lanes (same lg group) sharing each row.
#pragma unroll
    for (int r2 = 0; r2 < 2; ++r2)
#pragma unroll
        for (int i = 0; i < 4; ++i) {
            float v = bv[r2][i], v2 = bv2[r2][i];
            int ix = bi[r2][i];
#pragma unroll
            for (int off = 1; off < 16; off <<= 1) {
                float ov = __shfl_xor(v, off, 64);
                float ov2 = __shfl_xor(v2, off, 64);
                int oi = __shfl_xor(ix, off, 64);
                float nv2 = fminf(fminf(v2, ov2), fmaxf(v, ov));
                if (ov < v || (ov == v && oi < ix)) { v = ov; ix = oi; }
                v2 = nv2;
            }
            if (l15 == 0) {
                int row = wrow + r2 * 16 + lg * 4 + i;
                out_idx_f[row] = (float)ix;
                if (v2 - v < MARGIN) {
                    int pos = atomicAdd(rcnt, 1);
                    repair_rows[pos] = row;
                }
            }
        }
}

// ---------------------------------------------------------------------------
// Repair: exact f32 re-rank (R2-verified math) for flagged rows. 1 wave/row.
__global__ __launch_bounds__(256) void vq_repair(const float* __restrict__ x,
                                                 const float* __restrict__ cw,
                                                 const float* __restrict__ cnorm,
                                                 const int* __restrict__ rcnt,
                                                 const int* __restrict__ repair_rows,
                                                 float* __restrict__ out_idx_f) {
    const int lane = threadIdx.x & 63;
    const int wid = blockIdx.x * 4 + (threadIdx.x >> 6);
    const int count = *rcnt;
    for (int w = wid; w < count; w += 512) {
        int row = repair_rows[w];
        const float4* xr = reinterpret_cast<const float4*>(x + (size_t)row * D);
        float bv = 3.4e38f;
        int bi = 0;
        for (int g = 0; g < 16; ++g) {
            int k = g * 64 + lane;
            const float4* cr = reinterpret_cast<const float4*>(cw + (size_t)k * D);
            float dot = 0.f;
#pragma unroll 8
            for (int d4 = 0; d4 < 32; ++d4) {
                float4 cv = cr[d4];
                float4 xv = xr[d4];  // broadcast (uniform addr per wave)
                dot += xv.x * cv.x;
                dot += xv.y * cv.y;
                dot += xv.z * cv.z;
                dot += xv.w * cv.w;
            }
            float sc = cnorm[k] - 2.f * dot;
            if (sc < bv) { bv = sc; bi = k; }   // ascending k -> first-min
        }
#pragma unroll
        for (int off = 1; off < 64; off <<= 1) {
            float ov = __shfl_xor(bv, off, 64);
            int oi = __shfl_xor(bi, off, 64);
            if (ov < bv || (ov == bv && oi < bi)) { bv = ov; bi = oi; }
        }
        if (lane == 0) out_idx_f[row] = (float)bi;
    }
}

// ---------------------------------------------------------------------------
// Gather + straight-through + per-block partial squared-error (no atomics).
__global__ __launch_bounds__(256) void vq_gather_loss(const float* __restrict__ x,
                                                      const float* __restrict__ cw,
                                                      const float* __restrict__ idx_f,
                                                      float* __restrict__ qout,
                                                      double* __restrict__ partials) {
    const int total4 = N_ROWS * D / 4;
    double lsum = 0.0;
    for (int i = blockIdx.x * blockDim.x + threadIdx.x; i < total4;
         i += gridDim.x * blockDim.x) {
        int n = i >> 5;
        int d4 = i & 31;
        int k = (int)idx_f[n];
        float4 q = reinterpret_cast<const float4*>(cw + (size_t)k * D)[d4];
        float4 xv = reinterpret_cast<const float4*>(x)[i];
        float dxx = q.x - xv.x, dxy = q.y - xv.y, dxz = q.z - xv.z, dxw = q.w - xv.w;
        float4 o;
        o.x = xv.x + dxx; o.y = xv.y + dxy; o.z = xv.z + dxz; o.w = xv.w + dxw;
        reinterpret_cast<float4*>(qout)[i] = o;
        lsum += (double)(dxx * dxx + dxy * dxy + dxz * dxz + dxw * dxw);
    }
#pragma unroll
    for (int off = 32; off; off >>= 1) lsum += __shfl_down(lsum, off, 64);
    __shared__ double wsum[4];
    if ((threadIdx.x & 63) == 0) wsum[threadIdx.x >> 6] = lsum;
    __syncthreads();
    if (threadIdx.x == 0)
        partials[blockIdx.x] = wsum[0] + wsum[1] + wsum[2] + wsum[3];
}

// ---------------------------------------------------------------------------
__global__ __launch_bounds__(256) void vq_finalize(const double* __restrict__ partials,
                                                   float* __restrict__ out_loss) {
    double s = 0.0;
    for (int i = threadIdx.x; i < 2048; i += 256) s += partials[i];
#pragma unroll
    for (int off = 32; off; off >>= 1) s += __shfl_down(s, off, 64);
    __shared__ double wsum[4];
    if ((threadIdx.x & 63) == 0) wsum[threadIdx.x >> 6] = s;
    __syncthreads();
    if (threadIdx.x == 0)
        *out_loss = (float)((wsum[0] + wsum[1] + wsum[2] + wsum[3]) *
                            (1.25 / (double)((size_t)N_ROWS * D)));
}

// ---------------------------------------------------------------------------
extern "C" void kernel_launch(void* const* d_in, const int* in_sizes, int n_in,
                              void* d_out, int out_size, void* d_ws, size_t ws_size,
                              hipStream_t stream) {
    const float* x = (const float*)d_in[0];
    const float* cw = (const float*)d_in[1];

    float* qout = (float*)d_out;                                    // 8388608 f32
    float* out_idx_f = qout + (size_t)N_ROWS * D;                   // 65536 f32
    float* out_loss = out_idx_f + N_ROWS;                           // 1 f32

    const size_t XP_BYTES = 33554432;  // 2 planes x 8388608 bf16
    char* wsb = (char*)d_ws;
    unsigned short* Xp;
    char* rest;
    if (ws_size >= XP_BYTES + (2u << 20)) {
        Xp = (unsigned short*)wsb;
        rest = wsb + XP_BYTES;
    } else {
        // quantized region doubles as X-plane scratch; gather overwrites it last
        Xp = (unsigned short*)qout;
        rest = wsb;
    }
    unsigned short* Cp = (unsigned short*)rest;                      // 524288 B
    float* cnorm = (float*)(rest + 524288);                          // 4 KB
    int* rcnt = (int*)(rest + 524288 + 4096);                        // 16 B
    int* rrows = (int*)(rest + 524288 + 4096 + 16);                  // 256 KB
    double* partials = (double*)(rest + 524288 + 4096 + 16 + 262144);// 16 KB

    vq_prep_cw<<<K_CODES, 64, 0, stream>>>(cw, Cp, cnorm, rcnt);
    vq_prep_x<<<4096, 256, 0, stream>>>(x, Xp);
    vq_argmin_mfma<<<N_ROWS / 128, 256, 0, stream>>>(Xp, Cp, cnorm, out_idx_f, rcnt, rrows);
    vq_repair<<<128, 256, 0, stream>>>(x, cw, cnorm, rcnt, rrows, out_idx_f);
    vq_gather_loss<<<2048, 256, 0, stream>>>(x, cw, out_idx_f, qout, partials);
    vq_finalize<<<1, 256, 0, stream>>>(partials, out_loss);
}

// Round 4
// 212.789 us; speedup vs baseline: 2.0847x; 1.5775x over previous
//
#include <hip/hip_runtime.h>
#include <stdint.h>

// VectorQuantizer: N=65536 rows, D=128, K=1024 codewords, f32.
// d_out (all f32): quantized (8388608) | indices-as-float (65536) | loss (1)
//
// score = ||c||^2 - 2 x.c via bf16-split MFMA (hi*hi + hi*lo + lo*hi), fused
// per-row top-2; rows with margin < MARGIN re-ranked exactly in f32 (repair).

typedef short     bf16x8 __attribute__((ext_vector_type(8)));
typedef float     f32x4  __attribute__((ext_vector_type(4)));
typedef unsigned short u16x8 __attribute__((ext_vector_type(8)));
typedef unsigned short u16x2 __attribute__((ext_vector_type(2)));

constexpr int N_ROWS = 65536;
constexpr int K_CODES = 1024;
constexpr int D = 128;
constexpr float MARGIN = 0.03f;   // >> 30x worst-case bf16-split score error (~1e-3)

__device__ __forceinline__ unsigned short f32_to_bf16_rn(float f) {
    unsigned u = __float_as_uint(f);
    unsigned r = (u + 0x7FFFu + ((u >> 16) & 1u)) >> 16;
    return (unsigned short)r;
}
__device__ __forceinline__ float bf16_to_f32(unsigned short h) {
    return __uint_as_float(((unsigned)h) << 16);
}

__device__ __forceinline__ void gload_lds16(const void* g, void* l) {
    __builtin_amdgcn_global_load_lds(
        (const __attribute__((address_space(1))) unsigned int*)g,
        (__attribute__((address_space(3))) unsigned int*)l, 16, 0, 0);
}

// ---------------------------------------------------------------------------
// Prep: codeword norms (verified f32 math) + bf16 hi/lo planes; zero rcnt.
// Cp layout: [plane(2)][1024][128] bf16, plane stride 131072 elems.
__global__ __launch_bounds__(64) void vq_prep_cw(const float* __restrict__ cw,
                                                 unsigned short* __restrict__ Cp,
                                                 float* __restrict__ cnorm,
                                                 int* __restrict__ rcnt) {
    const int k = blockIdx.x;
    const int lane = threadIdx.x;
    float2 v = reinterpret_cast<const float2*>(cw + (size_t)k * D)[lane];
    float s = v.x * v.x + v.y * v.y;
#pragma unroll
    for (int off = 32; off; off >>= 1) s += __shfl_down(s, off, 64);
    if (lane == 0) cnorm[k] = s;
    if (lane == 0 && k == 0) *rcnt = 0;

    unsigned short hx = f32_to_bf16_rn(v.x), hy = f32_to_bf16_rn(v.y);
    unsigned short lx = f32_to_bf16_rn(v.x - bf16_to_f32(hx));
    unsigned short ly = f32_to_bf16_rn(v.y - bf16_to_f32(hy));
    size_t off0 = (size_t)k * D + lane * 2;
    u16x2 hv; hv[0] = hx; hv[1] = hy;
    u16x2 lv; lv[0] = lx; lv[1] = ly;
    *reinterpret_cast<u16x2*>(Cp + off0) = hv;
    *reinterpret_cast<u16x2*>(Cp + 131072 + off0) = lv;
}

// ---------------------------------------------------------------------------
// Main: fused MFMA score + per-row top-2 argmin. X converted bf16 in-kernel.
// Block = 256 thr (4 waves), BM=128 rows (32/wave), chunks of 64 codewords.
__global__ __launch_bounds__(256, 2) void vq_argmin_mfma(
    const float* __restrict__ x,
    const unsigned short* __restrict__ Cp,
    const float* __restrict__ cnorm,
    float* __restrict__ out_idx_f,
    int* __restrict__ rcnt,
    int* __restrict__ repair_rows) {
    __shared__ unsigned char Bs[2][2][16384];  // [buf][plane][col*256 + swz kbyte]

    const int tid = threadIdx.x;
    const int wave = tid >> 6;
    const int lane = tid & 63;
    const int l15 = lane & 15;
    const int lg = lane >> 4;
    const int wrow = blockIdx.x * 128 + wave * 32;

    // Kick off first B-tile staging before the A conversion work.
    const char* Cpb = reinterpret_cast<const char*>(Cp);
    auto stageB = [&](int c, int b) {
#pragma unroll
        for (int u = 0; u < 8; ++u) {
            int t = wave * 8 + u;
            int pl = t >> 4;
            int cwl = (t & 15) * 4 + lg;
            int q = l15 * 16;
            const char* src = Cpb + pl * 262144 + ((size_t)(c * 64 + cwl)) * 256
                              + (q ^ ((cwl & 7) << 4));
            void* dst = (void*)&Bs[b][pl][(t & 15) * 1024];
            gload_lds16(src, dst);
        }
    };
    stageB(0, 0);

    // ---- A fragments: read f32 x directly, split to bf16 hi/lo in registers.
    // Lane (l15, lg) of fragment (r2, s) holds row wrow+r2*16+l15, k = s*32+lg*8..+7.
    bf16x8 A[2][4][2];
#pragma unroll
    for (int r2 = 0; r2 < 2; ++r2) {
        const float* xr0 = x + (size_t)(wrow + r2 * 16 + l15) * D;
#pragma unroll
        for (int s = 0; s < 4; ++s) {
            const float4* xf = reinterpret_cast<const float4*>(xr0 + s * 32 + lg * 8);
            float4 f0 = xf[0];
            float4 f1 = xf[1];
            float in[8] = {f0.x, f0.y, f0.z, f0.w, f1.x, f1.y, f1.z, f1.w};
            u16x8 hv, lv;
#pragma unroll
            for (int e = 0; e < 8; ++e) {
                unsigned short h = f32_to_bf16_rn(in[e]);
                hv[e] = h;
                lv[e] = f32_to_bf16_rn(in[e] - bf16_to_f32(h));
            }
            A[r2][s][0] = *reinterpret_cast<bf16x8*>(&hv);
            A[r2][s][1] = *reinterpret_cast<bf16x8*>(&lv);
        }
    }

    float bv[2][4], bv2[2][4];
    int bi[2][4];
#pragma unroll
    for (int r2 = 0; r2 < 2; ++r2)
#pragma unroll
        for (int i = 0; i < 4; ++i) { bv[r2][i] = 3.4e38f; bv2[r2][i] = 3.4e38f; bi[r2][i] = 0; }

    // Per-lane swizzled read addressing within a plane.
    const int cbase = l15 * 256;
    const int swz = (l15 & 7) << 4;
    int kb[4];
#pragma unroll
    for (int s = 0; s < 4; ++s) kb[s] = (s * 64 + lg * 16) ^ swz;

    asm volatile("s_waitcnt vmcnt(0)" ::: "memory");
    __syncthreads();

    for (int c = 0; c < 16; ++c) {
        const int buf = c & 1;
        if (c < 15) stageB(c + 1, buf ^ 1);

        f32x4 acc[2][4];
#pragma unroll
        for (int r2 = 0; r2 < 2; ++r2)
#pragma unroll
            for (int j = 0; j < 4; ++j) acc[r2][j] = (f32x4)(0.f);

#pragma unroll
        for (int s = 0; s < 4; ++s) {
            bf16x8 bh[4], bl[4];
#pragma unroll
            for (int j = 0; j < 4; ++j) {
                int ad = j * 4096 + cbase + kb[s];
                bh[j] = *reinterpret_cast<const bf16x8*>(&Bs[buf][0][ad]);
                bl[j] = *reinterpret_cast<const bf16x8*>(&Bs[buf][1][ad]);
            }
#pragma unroll
            for (int r2 = 0; r2 < 2; ++r2)
#pragma unroll
                for (int j = 0; j < 4; ++j) {
                    acc[r2][j] = __builtin_amdgcn_mfma_f32_16x16x32_bf16(
                        A[r2][s][0], bh[j], acc[r2][j], 0, 0, 0);
                    acc[r2][j] = __builtin_amdgcn_mfma_f32_16x16x32_bf16(
                        A[r2][s][0], bl[j], acc[r2][j], 0, 0, 0);
                    acc[r2][j] = __builtin_amdgcn_mfma_f32_16x16x32_bf16(
                        A[r2][s][1], bh[j], acc[r2][j], 0, 0, 0);
                }
        }

        // scores + running top-2 (cols ascend per lane -> first-min kept)
#pragma unroll
        for (int j = 0; j < 4; ++j) {
            int col = c * 64 + j * 16 + l15;
            float cn = cnorm[col];
#pragma unroll
            for (int r2 = 0; r2 < 2; ++r2)
#pragma unroll
                for (int i = 0; i < 4; ++i) {
                    float sc = cn - 2.f * acc[r2][j][i];
                    if (sc < bv[r2][i]) {
                        bv2[r2][i] = bv[r2][i];
                        bv[r2][i] = sc;
                        bi[r2][i] = col;
                    } else if (sc < bv2[r2][i]) {
                        bv2[r2][i] = sc;
                    }
                }
        }
        asm volatile("s_waitcnt vmcnt(0)" ::: "memory");
        __syncthreads();
    }

    // Cross-lane top-2 merge over the 16 lanes (same lg group) sharing each row.
#pragma unroll
    for (int r2 = 0; r2 < 2; ++r2)
#pragma unroll
        for (int i = 0; i < 4; ++i) {
            float v = bv[r2][i], v2 = bv2[r2][i];
            int ix = bi[r2][i];
#pragma unroll
            for (int off = 1; off < 16; off <<= 1) {
                float ov = __shfl_xor(v, off, 64);
                float ov2 = __shfl_xor(v2, off, 64);
                int oi = __shfl_xor(ix, off, 64);
                float nv2 = fminf(fminf(v2, ov2), fmaxf(v, ov));
                if (ov < v || (ov == v && oi < ix)) { v = ov; ix = oi; }
                v2 = nv2;
            }
            if (l15 == 0) {
                int row = wrow + r2 * 16 + lg * 4 + i;
                out_idx_f[row] = (float)ix;
                if (v2 - v < MARGIN) {
                    int pos = atomicAdd(rcnt, 1);
                    repair_rows[pos] = row;
                }
            }
        }
}

// ---------------------------------------------------------------------------
// Repair: exact f32 re-rank for flagged rows. One row per block-iteration,
// 256 threads x 4 codewords each; x row broadcast from LDS. Codebook is
// L2-resident (just streamed by argmin), so the strided reads are cheap.
__global__ __launch_bounds__(256) void vq_repair(const float* __restrict__ x,
                                                 const float* __restrict__ cw,
                                                 const float* __restrict__ cnorm,
                                                 const int* __restrict__ rcnt,
                                                 const int* __restrict__ repair_rows,
                                                 float* __restrict__ out_idx_f) {
    const int tid = threadIdx.x;
    const int count = *rcnt;
    __shared__ float xs[128];
    __shared__ float rv[4];
    __shared__ int ri[4];
    for (int w = blockIdx.x; w < count; w += 2048) {
        int row = repair_rows[w];
        if (w != (int)blockIdx.x) __syncthreads();  // xs reuse guard
        if (tid < 32)
            reinterpret_cast<float4*>(xs)[tid] =
                reinterpret_cast<const float4*>(x + (size_t)row * D)[tid];
        __syncthreads();

        float bv = 3.4e38f;
        int bi = 0;
#pragma unroll
        for (int g = 0; g < 4; ++g) {
            int k = g * 256 + tid;  // ascending per thread -> first-min kept
            const float4* cr = reinterpret_cast<const float4*>(cw + (size_t)k * D);
            float dot = 0.f;
#pragma unroll 8
            for (int d4 = 0; d4 < 32; ++d4) {
                float4 cv = cr[d4];
                float4 xv = reinterpret_cast<const float4*>(xs)[d4];
                dot += xv.x * cv.x;
                dot += xv.y * cv.y;
                dot += xv.z * cv.z;
                dot += xv.w * cv.w;
            }
            float sc = cnorm[k] - 2.f * dot;
            if (sc < bv) { bv = sc; bi = k; }
        }
#pragma unroll
        for (int off = 1; off < 64; off <<= 1) {
            float ov = __shfl_xor(bv, off, 64);
            int oi = __shfl_xor(bi, off, 64);
            if (ov < bv || (ov == bv && oi < bi)) { bv = ov; bi = oi; }
        }
        if ((tid & 63) == 0) { rv[tid >> 6] = bv; ri[tid >> 6] = bi; }
        __syncthreads();
        if (tid == 0) {
            float fv = rv[0];
            int fi = ri[0];
#pragma unroll
            for (int q = 1; q < 4; ++q)
                if (rv[q] < fv || (rv[q] == fv && ri[q] < fi)) { fv = rv[q]; fi = ri[q]; }
            out_idx_f[row] = (float)fi;
        }
    }
}

// ---------------------------------------------------------------------------
// Gather + straight-through + per-block partial squared-error (no atomics).
__global__ __launch_bounds__(256) void vq_gather_loss(const float* __restrict__ x,
                                                      const float* __restrict__ cw,
                                                      const float* __restrict__ idx_f,
                                                      float* __restrict__ qout,
                                                      double* __restrict__ partials) {
    const int total4 = N_ROWS * D / 4;
    double lsum = 0.0;
    for (int i = blockIdx.x * blockDim.x + threadIdx.x; i < total4;
         i += gridDim.x * blockDim.x) {
        int n = i >> 5;
        int d4 = i & 31;
        int k = (int)idx_f[n];
        float4 q = reinterpret_cast<const float4*>(cw + (size_t)k * D)[d4];
        float4 xv = reinterpret_cast<const float4*>(x)[i];
        float dxx = q.x - xv.x, dxy = q.y - xv.y, dxz = q.z - xv.z, dxw = q.w - xv.w;
        float4 o;
        o.x = xv.x + dxx; o.y = xv.y + dxy; o.z = xv.z + dxz; o.w = xv.w + dxw;
        reinterpret_cast<float4*>(qout)[i] = o;
        lsum += (double)(dxx * dxx + dxy * dxy + dxz * dxz + dxw * dxw);
    }
#pragma unroll
    for (int off = 32; off; off >>= 1) lsum += __shfl_down(lsum, off, 64);
    __shared__ double wsum[4];
    if ((threadIdx.x & 63) == 0) wsum[threadIdx.x >> 6] = lsum;
    __syncthreads();
    if (threadIdx.x == 0)
        partials[blockIdx.x] = wsum[0] + wsum[1] + wsum[2] + wsum[3];
}

// ---------------------------------------------------------------------------
__global__ __launch_bounds__(256) void vq_finalize(const double* __restrict__ partials,
                                                   float* __restrict__ out_loss) {
    double s = 0.0;
    for (int i = threadIdx.x; i < 2048; i += 256) s += partials[i];
#pragma unroll
    for (int off = 32; off; off >>= 1) s += __shfl_down(s, off, 64);
    __shared__ double wsum[4];
    if ((threadIdx.x & 63) == 0) wsum[threadIdx.x >> 6] = s;
    __syncthreads();
    if (threadIdx.x == 0)
        *out_loss = (float)((wsum[0] + wsum[1] + wsum[2] + wsum[3]) *
                            (1.25 / (double)((size_t)N_ROWS * D)));
}

// ---------------------------------------------------------------------------
extern "C" void kernel_launch(void* const* d_in, const int* in_sizes, int n_in,
                              void* d_out, int out_size, void* d_ws, size_t ws_size,
                              hipStream_t stream) {
    const float* x = (const float*)d_in[0];
    const float* cw = (const float*)d_in[1];

    float* qout = (float*)d_out;                                    // 8388608 f32
    float* out_idx_f = qout + (size_t)N_ROWS * D;                   // 65536 f32
    float* out_loss = out_idx_f + N_ROWS;                           // 1 f32

    // Scratch layout: Cp 512KB | cnorm 4KB | rcnt 16B(+pad) | rrows 256KB | partials 16KB
    char* rest;
    if (ws_size >= (2u << 20)) {
        rest = (char*)d_ws;
    } else {
        // fall back to the quantized output region (gather overwrites it last)
        rest = (char*)qout;
    }
    unsigned short* Cp = (unsigned short*)rest;                       // 524288 B
    float* cnorm = (float*)(rest + 524288);                           // 4 KB
    int* rcnt = (int*)(rest + 524288 + 4096);                         // 16 B
    int* rrows = (int*)(rest + 524288 + 4096 + 256);                  // 256 KB
    double* partials = (double*)(rest + 524288 + 4096 + 256 + 262144);// 16 KB

    vq_prep_cw<<<K_CODES, 64, 0, stream>>>(cw, Cp, cnorm, rcnt);
    vq_argmin_mfma<<<N_ROWS / 128, 256, 0, stream>>>(x, Cp, cnorm, out_idx_f, rcnt, rrows);
    vq_repair<<<2048, 256, 0, stream>>>(x, cw, cnorm, rcnt, rrows, out_idx_f);
    vq_gather_loss<<<2048, 256, 0, stream>>>(x, cw, out_idx_f, qout, partials);
    vq_finalize<<<1, 256, 0, stream>>>(partials, out_loss);
}